// Round 1
// baseline (1494.367 us; speedup 1.0000x reference)
//
#include <hip/hip_runtime.h>
#include <math.h>

// Problem constants (from reference)
#define BSZ 4096
#define HL  20
#define NF  128
#define DM  640      // 3*NF + EF + TF
#define DIN 512      // DM - TF
#define DH  320      // DM / NHEAD

static __device__ __forceinline__ float sigmoidf_(float x){ return 1.f/(1.f+expf(-x)); }

// ---------------------------------------------------------------------------
// T1: combT[jc*128+jq] = (outfn_w @ out_proj_w)[jq, jc]
//     comb[jq,jc] = sum_e outfn_w[jq,e] * out_proj_w[e,jc]
// grid 640, block 128
__global__ void k_comb(const float* __restrict__ outfn_w,
                       const float* __restrict__ out_proj_w,
                       float* __restrict__ combT)
{
    int jc = blockIdx.x, jq = threadIdx.x;
    float acc = 0.f;
    for (int e = 0; e < DM; ++e)
        acc += outfn_w[jq*DM + e] * out_proj_w[e*DM + jc];
    combT[jc*NF + jq] = acc;
}

// T2: ZZ[ef*128+jq] = sum_dd Wv[h*320+dd, e] * combT[(h*320+dd)*128 + jq]
//     ef = h*640 + e ; Wv row = in_proj_w row (1280 + h*320 + dd)
// grid 1280, block 128
__global__ void k_zz(const float* __restrict__ in_proj_w,
                     const float* __restrict__ combT,
                     float* __restrict__ ZZ)
{
    int ef = blockIdx.x;
    int h = ef / DM, e = ef - h*DM;
    int jq = threadIdx.x;
    const float* wv = in_proj_w + (2*DM + h*DH)*DM + e;   // + dd*DM
    const float* cb = combT + (h*DH)*NF + jq;             // + dd*NF
    float acc = 0.f;
    for (int dd = 0; dd < DH; ++dd)
        acc += wv[dd*DM] * cb[dd*NF];
    ZZ[ef*NF + jq] = acc;
}

// T3: qbias[jq] = outfn_b[jq] + sum_e bout[e]*outfn_w[jq,e] + sum_jc bv[jc]*combT[jc,jq]
// grid 1, block 128
__global__ void k_qbias(const float* __restrict__ outfn_b,
                        const float* __restrict__ out_proj_b,
                        const float* __restrict__ outfn_w,
                        const float* __restrict__ in_proj_b,
                        const float* __restrict__ combT,
                        float* __restrict__ qb)
{
    int jq = threadIdx.x;
    float acc = outfn_b[jq];
    for (int e = 0; e < DM; ++e)  acc += out_proj_b[e] * outfn_w[jq*DM + e];
    for (int jc = 0; jc < DM; ++jc) acc += in_proj_b[2*DM + jc] * combT[jc*NF + jq];
    qb[jq] = acc;
}

// T4: transposes: giT[d*384+j] = gru_w_ih[j*512+d]; ghT[d*384+j] = gru_w_hh[j*128+d]
// grid 960, block 256  (960*256 = 512*384 + 128*384 exactly)
__global__ void k_transpose(const float* __restrict__ gih,
                            const float* __restrict__ ghh,
                            float* __restrict__ giT,
                            float* __restrict__ ghT)
{
    int i = blockIdx.x*blockDim.x + threadIdx.x;
    if (i < DIN*3*NF) {
        int d = i / (3*NF), j = i - d*(3*NF);
        giT[i] = gih[j*DIN + d];
    } else {
        int i2 = i - DIN*3*NF;   // < 128*384
        int d = i2 / (3*NF), j = i2 - d*(3*NF);
        ghT[i2] = ghh[j*NF + d];
    }
}

// K2a: qc[j] = in_proj_b[j] + sum_d cos(time_b[d]) * in_proj_w[j*640 + 512 + d]
// (zeroed last row of full_vals is [0 x512, cos(time_b)] for every b)
// grid 5, block 128
__global__ void k_qc(const float* __restrict__ time_b,
                     const float* __restrict__ in_proj_w,
                     const float* __restrict__ in_proj_b,
                     float* __restrict__ qcv)
{
    __shared__ float tsr[NF];
    int tid = threadIdx.x;
    tsr[tid] = cosf(time_b[tid]);
    __syncthreads();
    int j = blockIdx.x*128 + tid;   // < 640
    const float* wr = in_proj_w + j*DM + DIN;
    float acc = in_proj_b[j];
    for (int d = 0; d < NF; ++d) acc += tsr[d]*wr[d];
    qcv[j] = acc;
}

// K2a2: cc[h] = dot(qc_h, bk_h)   (bias fold-in for scores)
// grid 1, block 128 (2 waves, one per head)
__global__ void k_cc(const float* __restrict__ qcv,
                     const float* __restrict__ in_proj_b,
                     float* __restrict__ cc)
{
    int wave = threadIdx.x >> 6, lane = threadIdx.x & 63;
    float acc = 0.f;
    for (int j = lane; j < DH; j += 64)
        acc += qcv[wave*DH + j] * in_proj_b[DM + wave*DH + j];
    for (int off = 32; off > 0; off >>= 1) acc += __shfl_down(acc, off);
    if (lane == 0) cc[wave] = acc;
}

// K2b: u[h*640+d] = sum_j qc[h*320+j] * in_proj_w[(640+h*320+j)*640 + d]
// grid 20, block 64 (d = blockIdx*64+tid, h uniform per block)
__global__ void k_u(const float* __restrict__ qcv,
                    const float* __restrict__ in_proj_w,
                    float* __restrict__ u)
{
    int d = blockIdx.x*64 + threadIdx.x;   // < 1280
    int h = d / DM, dd = d - h*DM;
    const float* base = in_proj_w + (DM + h*DH)*DM + dd;  // + j*DM
    const float* q = qcv + h*DH;
    float acc = 0.f;
    for (int j = 0; j < DH; ++j) acc += q[j]*base[j*DM];
    u[d] = acc;
}

// ---------------------------------------------------------------------------
// K3: per-batch fused build + MHA attention (collapsed form).
// Builds zfull (zeroed last row) in LDS, writes last_event_feat,
// scores[h,m] = (u_h . zfull[m] + c_h)/sqrt(320), softmax,
// w[h,d] = sum_m attn[h,m]*zfull[m,d]  -> wbuf (b x 1280)
// grid 4096, block 256
__global__ __launch_bounds__(256) void k_attn1(
    const int* __restrict__ nids, const int* __restrict__ hist_nids,
    const int* __restrict__ aidsp, const int* __restrict__ eidsp,
    const float* __restrict__ hist_ts, const int* __restrict__ dirsp,
    const float* __restrict__ node_feat, const float* __restrict__ edge_feat,
    const float* __restrict__ anony_emb,
    const float* __restrict__ time_w, const float* __restrict__ time_b,
    const float* __restrict__ u, const float* __restrict__ cc,
    float* __restrict__ wbuf, float* __restrict__ lef)
{
    int b = blockIdx.x, tid = threadIdx.x;
    __shared__ float zf[HL][DM];      // 51.2 KB
    __shared__ float ul[2*DM];
    __shared__ float sc[2][HL];
    __shared__ float aw[2][HL];
    __shared__ int   shn[HL], sdir[HL], said[HL], seid[HL];
    __shared__ float sts[HL];

    if (tid < HL) {
        shn[tid]  = hist_nids[b*HL+tid];
        sdir[tid] = dirsp[b*HL+tid];
        said[tid] = aidsp[b*HL+tid];
        seid[tid] = eidsp[b*HL+tid];
        sts[tid]  = hist_ts[b*HL+tid];
    }
    for (int i = tid; i < 2*DM; i += 256) ul[i] = u[i];
    __syncthreads();

    int rnid = nids[b];
    float tlast = sts[HL-1];
    for (int l = 0; l < HL; ++l) {
        int hn = shn[l], dir = sdir[l];
        int srcn = dir ? rnid : hn;
        int dstn = dir ? hn : rnid;
        int aid = said[l], eid = seid[l];
        float dt = tlast - sts[l];
        for (int c = tid; c < DM; c += 256) {
            float v;
            if (c < NF)            v = node_feat[srcn*NF + c];
            else if (c < 2*NF)     v = node_feat[dstn*NF + (c-NF)];
            else if (c < 3*NF)     v = anony_emb[aid*NF + (c-2*NF)];
            else if (c < 4*NF)     v = edge_feat[eid*NF + (c-3*NF)];
            else { int d = c - 4*NF; v = cosf(dt*time_w[d] + time_b[d]); }
            if (l == HL-1 && c < DIN) { lef[b*DIN + c] = v; v = 0.f; }
            zf[l][c] = v;
        }
    }
    __syncthreads();

    int wave = tid >> 6, lane = tid & 63;
    float c0 = cc[0], c1 = cc[1];
    for (int pr = wave; pr < 2*HL; pr += 4) {
        int h = pr / HL, m = pr - h*HL;
        float acc = 0.f;
        for (int d = lane; d < DM; d += 64) acc += ul[h*DM + d]*zf[m][d];
        for (int off = 32; off > 0; off >>= 1) acc += __shfl_down(acc, off);
        if (lane == 0) {
            float s = (acc + (h ? c1 : c0)) * 0.05590169943749474f; // 1/sqrt(320)
            bool msk = (shn[m] == 0) && (m != HL-1);
            sc[h][m] = msk ? -1.0e9f : s;
        }
    }
    __syncthreads();
    if (tid < 2) {
        float mx = -3.0e38f;
        for (int m = 0; m < HL; ++m) mx = fmaxf(mx, sc[tid][m]);
        float sum = 0.f;
        for (int m = 0; m < HL; ++m) { float e = expf(sc[tid][m]-mx); aw[tid][m] = e; sum += e; }
        float inv = 1.f/sum;
        for (int m = 0; m < HL; ++m) aw[tid][m] *= inv;
    }
    __syncthreads();
    for (int i = tid; i < 2*DM; i += 256) {
        int h = i / DM, d = i - h*DM;
        float acc = 0.f;
        #pragma unroll
        for (int m = 0; m < HL; ++m) acc += aw[h][m]*zf[m][d];
        wbuf[b*2*DM + i] = acc;
    }
}

// ---------------------------------------------------------------------------
// Row-block GEMM: qn (4096 x 128) = wbuf (4096 x 1280) @ ZZ (1280 x 128) + qbias
// grid 512, block 256, 8 rows per block
__global__ __launch_bounds__(256) void k_gemm_qn(const float* __restrict__ A,
                                                 const float* __restrict__ BT,
                                                 const float* __restrict__ bias,
                                                 float* __restrict__ C)
{
    constexpr int K = 2*DM;  // 1280
    __shared__ float As[8*K];   // 40 KB
    int r0 = blockIdx.x*8, tid = threadIdx.x;
    for (int i = tid; i < 8*K; i += 256) As[i] = A[r0*K + i];  // rows contiguous
    __syncthreads();
    int j = tid & (NF-1), rh = tid >> 7;       // 2 row-halves of 4
    const float* bp = BT + j;
    const float* ap = As + rh*4*K;
    float acc0=0.f, acc1=0.f, acc2=0.f, acc3=0.f;
    for (int d = 0; d < K; ++d) {
        float bv = bp[d*NF];
        acc0 += ap[d]*bv;
        acc1 += ap[K + d]*bv;
        acc2 += ap[2*K + d]*bv;
        acc3 += ap[3*K + d]*bv;
    }
    float bsv = bias[j];
    int rb = r0 + rh*4;
    C[(rb+0)*NF + j] = acc0 + bsv;
    C[(rb+1)*NF + j] = acc1 + bsv;
    C[(rb+2)*NF + j] = acc2 + bsv;
    C[(rb+3)*NF + j] = acc3 + bsv;
}

// Row-block GEMM: gi (4096 x 384) = lef (4096 x 512) @ giT (512 x 384) + gru_b_ih
// grid 512, block 256, 8 rows per block
__global__ __launch_bounds__(256) void k_gemm_gi(const float* __restrict__ A,
                                                 const float* __restrict__ BT,
                                                 const float* __restrict__ bias,
                                                 float* __restrict__ C)
{
    constexpr int K = DIN;     // 512
    constexpr int N = 3*NF;    // 384
    __shared__ float As[8*K];  // 16 KB
    int r0 = blockIdx.x*8, tid = threadIdx.x;
    for (int i = tid; i < 8*K; i += 256) As[i] = A[r0*K + i];
    __syncthreads();
    int j0 = tid, j1 = tid + 256;
    bool has1 = (j1 < N);
    float a0[8] = {0,0,0,0,0,0,0,0};
    float a1[8] = {0,0,0,0,0,0,0,0};
    for (int d = 0; d < K; ++d) {
        float b0 = BT[d*N + j0];
        float b1 = 0.f;
        if (has1) b1 = BT[d*N + j1];
        #pragma unroll
        for (int r = 0; r < 8; ++r) {
            float av = As[r*K + d];
            a0[r] += av*b0;
            a1[r] += av*b1;
        }
    }
    float bs0 = bias[j0];
    for (int r = 0; r < 8; ++r) C[(r0+r)*N + j0] = a0[r] + bs0;
    if (has1) {
        float bs1 = bias[j1];
        for (int r = 0; r < 8; ++r) C[(r0+r)*N + j1] = a1[r] + bs1;
    }
}

// ---------------------------------------------------------------------------
// Tail: attention2 (collapsed) + merge + GRU + RK4 ODE.  grid 4096, block 128.
static __device__ __forceinline__ float ode_eval(float yin, const float4* wr,
                                                 float odebj, float ratio,
                                                 float* yv, int tid)
{
    __syncthreads();          // previous readers of yv done
    yv[tid] = yin;
    __syncthreads();
    float acc = odebj;
    #pragma unroll
    for (int i = 0; i < 32; ++i)
        acc += yv[4*i]*wr[i].x + yv[4*i+1]*wr[i].y + yv[4*i+2]*wr[i].z + yv[4*i+3]*wr[i].w;
    return tanhf(acc)*ratio;
}

__global__ __launch_bounds__(128) void k_tail(
    const int* __restrict__ nids, const int* __restrict__ hist_nids,
    const int* __restrict__ eidsp, const float* __restrict__ hist_ts,
    const float* __restrict__ node_feat, const float* __restrict__ edge_feat,
    const float* __restrict__ time_w, const float* __restrict__ time_b,
    const float* __restrict__ attn_wq, const float* __restrict__ attn_wk,
    const float* __restrict__ attn_wv,
    const float* __restrict__ merge_w, const float* __restrict__ merge_b,
    const float* __restrict__ qn, const float* __restrict__ gi,
    const float* __restrict__ ghT, const float* __restrict__ gru_b_hh,
    const float* __restrict__ ode_w, const float* __restrict__ ode_b,
    const float* __restrict__ tnode_w, const float* __restrict__ tnode_b,
    float* __restrict__ out)
{
    int b = blockIdx.x, tid = threadIdx.x;
    __shared__ float nb[HL][3*NF];   // 30.7 KB
    __shared__ float qh[NF];
    __shared__ float p[3*NF];
    __shared__ float scl[HL], al[HL];
    __shared__ float nbar[3*NF];
    __shared__ float ctx2[NF];
    __shared__ float hpl[NF];
    __shared__ float yv[NF];
    __shared__ float qns[NF];
    __shared__ float nfn[NF];
    __shared__ int   shn[HL], seid[HL];
    __shared__ float sts[HL];

    if (tid < HL) {
        shn[tid]  = hist_nids[b*HL+tid];
        seid[tid] = eidsp[b*HL+tid];
        sts[tid]  = hist_ts[b*HL+tid];
    }
    qns[tid] = qn[b*NF + tid];
    nfn[tid] = node_feat[nids[b]*NF + tid];
    __syncthreads();

    float tlast = sts[HL-1];
    float tw_ = time_w[tid], tb_ = time_b[tid];
    for (int l = 0; l < HL; ++l) {
        float dt = tlast - sts[l];
        nb[l][tid]        = node_feat[shn[l]*NF + tid];
        nb[l][tid+NF]     = edge_feat[seid[l]*NF + tid];
        nb[l][tid+2*NF]   = cosf(dt*tw_ + tb_);
    }
    // qh = qn @ attn_wq
    {
        float acc = 0.f;
        for (int d = 0; d < NF; ++d) acc += qns[d]*attn_wq[d*NF + tid];
        qh[tid] = acc;
    }
    __syncthreads();
    // p[d] = sum_j attn_wk[d,j]*qh[j]
    for (int dd = tid; dd < 3*NF; dd += NF) {
        const float4* row4 = (const float4*)(attn_wk + dd*NF);
        float acc = 0.f;
        #pragma unroll
        for (int q4 = 0; q4 < NF/4; ++q4) {
            float4 w4 = row4[q4];
            acc += w4.x*qh[4*q4] + w4.y*qh[4*q4+1] + w4.z*qh[4*q4+2] + w4.w*qh[4*q4+3];
        }
        p[dd] = acc;
    }
    __syncthreads();
    // sc[l] = nb[l].p / sqrt(128), masked
    int wave = tid >> 6, lane = tid & 63;
    for (int l = wave; l < HL; l += 2) {
        float acc = 0.f;
        for (int d = lane; d < 3*NF; d += 64) acc += p[d]*nb[l][d];
        for (int off = 32; off > 0; off >>= 1) acc += __shfl_down(acc, off);
        if (lane == 0) {
            bool msk = (shn[l] == 0) && (l != HL-1);
            scl[l] = msk ? -1.0e9f : acc*0.08838834764831845f;  // 1/sqrt(128)
        }
    }
    __syncthreads();
    if (tid == 0) {
        float mx = -3.0e38f;
        for (int m = 0; m < HL; ++m) mx = fmaxf(mx, scl[m]);
        float sum = 0.f;
        for (int m = 0; m < HL; ++m) { float e = expf(scl[m]-mx); al[m] = e; sum += e; }
        float inv = 1.f/sum;
        for (int m = 0; m < HL; ++m) al[m] *= inv;
    }
    __syncthreads();
    // nbar = sum_l a[l]*nb[l]
    for (int dd = tid; dd < 3*NF; dd += NF) {
        float acc = 0.f;
        #pragma unroll
        for (int m = 0; m < HL; ++m) acc += al[m]*nb[m][dd];
        nbar[dd] = acc;
    }
    __syncthreads();
    // ctx2 = nbar @ attn_wv
    {
        float acc = 0.f;
        for (int d = 0; d < 3*NF; ++d) acc += nbar[d]*attn_wv[d*NF + tid];
        ctx2[tid] = acc;
    }
    __syncthreads();
    // h_prev_left = tanh([ctx2; node_feat[nids]] @ merge_w + merge_b)
    {
        float acc = merge_b[tid];
        for (int d = 0; d < NF; ++d) acc += ctx2[d]*merge_w[d*NF + tid];
        for (int d = 0; d < NF; ++d) acc += nfn[d]*merge_w[(NF+d)*NF + tid];
        hpl[tid] = tanhf(acc);
    }
    __syncthreads();
    // GRU
    float ghv[3];
    #pragma unroll
    for (int s = 0; s < 3; ++s) {
        int jj = s*NF + tid;
        float acc = gru_b_hh[jj];
        for (int d = 0; d < NF; ++d) acc += hpl[d]*ghT[d*3*NF + jj];
        ghv[s] = acc;
    }
    float gi0 = gi[b*3*NF + tid];
    float gi1 = gi[b*3*NF + NF + tid];
    float gi2 = gi[b*3*NF + 2*NF + tid];
    float r_ = sigmoidf_(gi0 + ghv[0]);
    float z_ = sigmoidf_(gi1 + ghv[1]);
    float n_ = tanhf(gi2 + r_*ghv[2]);
    float hplj = hpl[tid];
    float hpr = (1.f - z_)*n_ + z_*hplj;
    out[BSZ*NF + b*NF + tid] = hpr;            // h_right
    // RK4 ODE (8 steps)
    float t0 = sts[HL-2];
    float ratio = tlast - t0;
    float4 wr[32];
    const float4* owr = (const float4*)(ode_w + tid*NF);
    #pragma unroll
    for (int i = 0; i < 32; ++i) wr[i] = owr[i];
    float twj = tnode_w[tid], tbj = tnode_b[tid], odebj = ode_b[tid];
    float z = hpr;
    const float dss = 0.125f;
    for (int i = 0; i < 8; ++i) {
        float s0 = i*dss;
        float te0 = cosf((s0*ratio + t0)*twj + tbj);
        float teh = cosf(((s0 + 0.5f*dss)*ratio + t0)*twj + tbj);
        float te1 = cosf(((s0 + dss)*ratio + t0)*twj + tbj);
        float k1 = ode_eval(z + te0,               wr, odebj, ratio, yv, tid);
        float k2 = ode_eval(z + 0.5f*dss*k1 + teh, wr, odebj, ratio, yv, tid);
        float k3 = ode_eval(z + 0.5f*dss*k2 + teh, wr, odebj, ratio, yv, tid);
        float k4 = ode_eval(z + dss*k3 + te1,      wr, odebj, ratio, yv, tid);
        z += (dss/6.f)*(k1 + 2.f*k2 + 2.f*k3 + k4);
    }
    out[b*NF + tid] = z;                       // h_left (invalid_rows is always all-False)
    if (tid == 0) out[2*BSZ*NF + b] = tlast;   // hist_ts[:, -1]
}

// ---------------------------------------------------------------------------
extern "C" void kernel_launch(void* const* d_in, const int* in_sizes, int n_in,
                              void* d_out, int out_size, void* d_ws, size_t ws_size,
                              hipStream_t stream)
{
    (void)in_sizes; (void)n_in; (void)out_size; (void)ws_size;
    const int*   nids      = (const int*)d_in[0];
    const int*   hist_nids = (const int*)d_in[2];
    const int*   aids      = (const int*)d_in[3];
    const int*   eids      = (const int*)d_in[4];
    const float* hist_ts   = (const float*)d_in[5];
    const int*   dirs      = (const int*)d_in[6];
    const float* node_feat = (const float*)d_in[7];
    const float* edge_feat = (const float*)d_in[8];
    const float* anony_emb = (const float*)d_in[9];
    const float* time_w    = (const float*)d_in[10];
    const float* time_b    = (const float*)d_in[11];
    const float* in_proj_w = (const float*)d_in[12];
    const float* in_proj_b = (const float*)d_in[13];
    const float* out_proj_w= (const float*)d_in[14];
    const float* out_proj_b= (const float*)d_in[15];
    const float* outfn_w   = (const float*)d_in[16];
    const float* outfn_b   = (const float*)d_in[17];
    const float* attn_wq   = (const float*)d_in[18];
    const float* attn_wk   = (const float*)d_in[19];
    const float* attn_wv   = (const float*)d_in[20];
    const float* merge_w   = (const float*)d_in[21];
    const float* merge_b   = (const float*)d_in[22];
    const float* gru_w_ih  = (const float*)d_in[23];
    const float* gru_w_hh  = (const float*)d_in[24];
    const float* gru_b_ih  = (const float*)d_in[25];
    const float* gru_b_hh  = (const float*)d_in[26];
    const float* ode_w     = (const float*)d_in[27];
    const float* ode_b     = (const float*)d_in[28];
    const float* tnode_w   = (const float*)d_in[29];
    const float* tnode_b   = (const float*)d_in[30];
    float* out = (float*)d_out;

    float* ws    = (float*)d_ws;
    float* qc    = ws;                   // 640
    float* cc    = ws + 640;             // 2
    float* u     = ws + 768;             // 1280
    float* wbuf  = ws + 2048;            // 4096*1280
    float* lef   = wbuf + BSZ*2*DM;      // 4096*512
    float* qn    = lef + BSZ*DIN;        // 4096*128
    float* gi    = qn + BSZ*NF;          // 4096*384
    float* combT = gi + BSZ*3*NF;        // 640*128
    float* ZZ    = combT + DM*NF;        // 1280*128
    float* qb    = ZZ + 2*DM*NF;         // 128
    float* giT   = qb + NF;              // 512*384
    float* ghT   = giT + DIN*3*NF;       // 128*384
    // total ~9.93M floats = 39.7 MB of d_ws

    // per-launch constant precomputes (inputs are restored before every launch)
    k_comb<<<DM, NF, 0, stream>>>(outfn_w, out_proj_w, combT);
    k_zz<<<2*DM, NF, 0, stream>>>(in_proj_w, combT, ZZ);
    k_qbias<<<1, NF, 0, stream>>>(outfn_b, out_proj_b, outfn_w, in_proj_b, combT, qb);
    k_transpose<<<960, 256, 0, stream>>>(gru_w_ih, gru_w_hh, giT, ghT);
    k_qc<<<5, 128, 0, stream>>>(time_b, in_proj_w, in_proj_b, qc);
    k_cc<<<1, 128, 0, stream>>>(qc, in_proj_b, cc);
    k_u<<<HL, 64, 0, stream>>>(qc, in_proj_w, u);

    // main pipeline
    k_attn1<<<BSZ, 256, 0, stream>>>(nids, hist_nids, aids, eids, hist_ts, dirs,
                                     node_feat, edge_feat, anony_emb,
                                     time_w, time_b, u, cc, wbuf, lef);
    k_gemm_qn<<<BSZ/8, 256, 0, stream>>>(wbuf, ZZ, qb, qn);
    k_gemm_gi<<<BSZ/8, 256, 0, stream>>>(lef, giT, gru_b_ih, gi);
    k_tail<<<BSZ, 128, 0, stream>>>(nids, hist_nids, eids, hist_ts,
                                    node_feat, edge_feat, time_w, time_b,
                                    attn_wq, attn_wk, attn_wv, merge_w, merge_b,
                                    qn, gi, ghT, gru_b_hh,
                                    ode_w, ode_b, tnode_w, tnode_b, out);
}